// Round 1
// baseline (7462.951 us; speedup 1.0000x reference)
//
#include <hip/hip_runtime.h>

#define T_STEPS 256
#define BATCH   25
#define VOCAB   32000
#define HID     1024

#define NPART   8                   // WGs per chain (N-split of hidden dim)
#define NCOLS   128                 // output columns per WG
#define NCHAIN  BATCH               // 25 independent batch chains
#define NWG     (NCHAIN * NPART)    // 200 workgroups

typedef _Float16 half8  __attribute__((ext_vector_type(8)));
typedef _Float16 half2v __attribute__((ext_vector_type(2)));
typedef float    floatx4  __attribute__((ext_vector_type(4)));

// ---------------------------------------------------------------------------
// ws layout (bytes) — unchanged footprint vs previous version:
//   P    : 6400*1024*4      = 26,214,400
//   Bt   : 1024*32000*2     = 65,536,000   (W_xh transposed, f16, [n][k])
//   H0   : 25*1024*2        = 51,200      (h double buffer, parity 0)
//   (pad to 65,536)
//   H1   : 25*1024*2        = 51,200      (h double buffer, parity 1)
//   FLG  : 200*4            = 800         (per-WG step flags, in hB slack)
// ---------------------------------------------------------------------------
#define OFF_BT  (26214400)
#define OFF_H0  (26214400 + 65536000)
#define OFF_H1  (OFF_H0 + 65536)
#define OFF_FLG (OFF_H1 + 51200)

// ===========================================================================
// K1: transpose-convert W_xh (32000 x 1024 fp32) -> Bt (1024 x 32000 f16)
// Also zero-inits the k_rec flag array (runs first on the stream).
// ===========================================================================
__global__ __launch_bounds__(256) void k_transpose(const float* __restrict__ W,
                                                   _Float16* __restrict__ Bt,
                                                   int* __restrict__ flags) {
    if (blockIdx.x == 0 && blockIdx.y == 0 && threadIdx.x < NWG)
        flags[threadIdx.x] = 0;
    __shared__ _Float16 tile[64][72];   // +8 pad to break bank conflicts
    const int k0 = blockIdx.x * 64;
    const int n0 = blockIdx.y * 64;
    const int t  = threadIdx.x;
    #pragma unroll
    for (int i = 0; i < 4; ++i) {
        int s  = t + i * 256;           // 0..1023
        int r  = s >> 4;                // k row in tile
        int c4 = (s & 15) * 4;          // n col in tile
        const float4 v = *(const float4*)(W + (size_t)(k0 + r) * HID + n0 + c4);
        tile[r][c4 + 0] = (_Float16)v.x;
        tile[r][c4 + 1] = (_Float16)v.y;
        tile[r][c4 + 2] = (_Float16)v.z;
        tile[r][c4 + 3] = (_Float16)v.w;
    }
    __syncthreads();
    #pragma unroll
    for (int i = 0; i < 2; ++i) {
        int s  = t + i * 256;           // 0..511
        int nr = s >> 3;                // n row in tile
        int k8 = (s & 7) * 8;
        half8 h;
        #pragma unroll
        for (int j = 0; j < 8; ++j) h[j] = tile[k8 + j][nr];
        *(half8*)(Bt + (size_t)(n0 + nr) * VOCAB + k0 + k8) = h;
    }
}

// ===========================================================================
// K2: P = X @ W_xh  via f16 MFMA.  M=6400 (=T*B), K=32000, N=1024.
// (unchanged this round)
// ===========================================================================
__global__ __launch_bounds__(256) void k_gemm(const float* __restrict__ X,
                                              const _Float16* __restrict__ Bt,
                                              float* __restrict__ P) {
    const int bid = blockIdx.x;
    const int c   = bid & 7;
    const int j   = bid >> 3;
    const int mt  = (j >> 3) * 8 + c;   // M-tile
    const int nt  = j & 7;              // N-tile
    if (mt >= 50) return;
    const int m0 = mt * 128, n0 = nt * 128;

    __shared__ _Float16 sA[4096];   // 8 KB
    __shared__ _Float16 sB[4096];   // 8 KB

    const int tid  = threadIdx.x;
    const int lane = tid & 63;
    const int wv   = tid >> 6;       // wave 0..3
    const int wm   = wv >> 1;        // 0..1 (m half)
    const int wn   = wv & 1;         // 0..1 (n half)

    floatx4 acc[4][4];
    #pragma unroll
    for (int i = 0; i < 4; ++i)
        #pragma unroll
        for (int jj = 0; jj < 4; ++jj) acc[i][jj] = 0.0f;

    for (int kc = 0; kc < VOCAB / 32; ++kc) {
        const int k0 = kc * 32;
        __syncthreads();
        #pragma unroll
        for (int r = 0; r < 2; ++r) {
            int s  = tid + r * 256;          // 0..511
            int m  = s >> 2;                 // row in tile (0..127)
            int ko = s & 3;                  // k-octet (0..3)
            const float4* gp = (const float4*)(X + (size_t)(m0 + m) * VOCAB + k0 + ko * 8);
            float4 v0 = gp[0], v1 = gp[1];
            half8 ha;
            ha[0] = (_Float16)v0.x; ha[1] = (_Float16)v0.y;
            ha[2] = (_Float16)v0.z; ha[3] = (_Float16)v0.w;
            ha[4] = (_Float16)v1.x; ha[5] = (_Float16)v1.y;
            ha[6] = (_Float16)v1.z; ha[7] = (_Float16)v1.w;
            int ti = m >> 4;
            int li = (ko << 4) | (m & 15);   // fragment lane
            *(half8*)&sA[ti * 512 + li * 8] = ha;
            half8 hb = *(const half8*)(Bt + (size_t)(n0 + m) * VOCAB + k0 + ko * 8);
            *(half8*)&sB[ti * 512 + li * 8] = hb;
        }
        __syncthreads();
        half8 af[4], bf[4];
        #pragma unroll
        for (int i = 0; i < 4; ++i) af[i] = *(const half8*)&sA[(wm * 4 + i) * 512 + lane * 8];
        #pragma unroll
        for (int i = 0; i < 4; ++i) bf[i] = *(const half8*)&sB[(wn * 4 + i) * 512 + lane * 8];
        #pragma unroll
        for (int i = 0; i < 4; ++i)
            #pragma unroll
            for (int jj = 0; jj < 4; ++jj)
                acc[i][jj] = __builtin_amdgcn_mfma_f32_16x16x32_f16(af[i], bf[jj], acc[i][jj], 0, 0, 0);
    }

    const int quad = lane >> 4, col = lane & 15;
    #pragma unroll
    for (int i = 0; i < 4; ++i) {
        int mg = m0 + wm * 64 + i * 16 + quad * 4;
        #pragma unroll
        for (int jj = 0; jj < 4; ++jj) {
            int ng = n0 + wn * 64 + jj * 16 + col;
            #pragma unroll
            for (int r = 0; r < 4; ++r)
                P[(size_t)(mg + r) * HID + ng] = acc[i][jj][r];
        }
    }
}

// ===========================================================================
// f32 += dot(2xf16, 2xf16)
// ===========================================================================
static __device__ __forceinline__ float dot2(half2v a, half2v b, float c) {
#if __has_builtin(__builtin_amdgcn_fdot2)
    return __builtin_amdgcn_fdot2(a, b, c, false);
#else
    return c + (float)a[0] * (float)b[0] + (float)a[1] * (float)b[1];
#endif
}

// ===========================================================================
// K3: batch-split persistent recurrence.
// 25 independent chains (one per batch row) x 8 WGs x 256 threads.
// WG (b, j) owns output columns [j*128, j*128+128) of chain b, and holds its
// W_hh slice (1024 x 128 f16) in registers: thread t holds column (t&127),
// K-half (t>>7) -> 512 halves = 64 x half8 = 256 VGPRs.
// Per step: prefetch P, poll 7 producer flags (no contended counter), stage
// 2 KB h to LDS, 256 v_dot2_f32_f16 (4 acc chains), LDS K-reduce, tanh,
// 256 B slice store, release flag.  No grid barrier anywhere.
// ===========================================================================
__global__ __launch_bounds__(256, 1) void k_rec(const float* __restrict__ P,
                                                const float* __restrict__ Whh,
                                                const float* __restrict__ bh,
                                                const float* __restrict__ fcw,
                                                const float* __restrict__ fcb,
                                                _Float16* __restrict__ H0,
                                                _Float16* __restrict__ H1,
                                                float* __restrict__ out,
                                                int* __restrict__ flags) {
    const int wg  = blockIdx.x;          // 0..199
    const int b   = wg >> 3;             // chain (batch row) 0..24
    const int j   = wg & 7;              // part 0..7
    const int n0  = j * NCOLS;
    const int tid = threadIdx.x;
    const int col = tid & (NCOLS - 1);   // 0..127
    const int kh  = tid >> 7;            // K-half 0/1
    const int kbase = kh * 512;          // element offset into h

    __shared__ alignas(16) _Float16 hsm[HID];   // staged h vector (2 KB)
    __shared__ float red[NCOLS];                // K-half partial sums

    // --- one-time: W_hh slice -> registers (64 x half8), coalesced across cols
    half8 wreg[64];
    {
        const float* wp = Whh + (size_t)kbase * HID + n0 + col;
        #pragma unroll
        for (int kk = 0; kk < 64; ++kk) {
            half8 h;
            #pragma unroll
            for (int q = 0; q < 8; ++q)
                h[q] = (_Float16)wp[(size_t)(kk * 8 + q) * HID];
            wreg[kk] = h;
        }
    }

    const float bhreg = bh[n0 + col];
    int* flg = flags + b * NPART;        // this chain's 8 flags (one 32B line)

    for (int t = 0; t < T_STEPS; ++t) {
        // P prefetch — independent of the inter-WG sync, issue before waiting
        float pval = P[((size_t)t * BATCH + b) * HID + n0 + col];
        float a0 = 0.f, a1 = 0.f, a2 = 0.f, a3 = 0.f;

        if (t > 0) {
            const _Float16* hin = ((t & 1) ? H1 : H0) + (size_t)b * HID;
            // wait for the 7 other parts of THIS chain (own flag set locally)
            if (tid < NPART && tid != j) {
                while (__hip_atomic_load(&flg[tid], __ATOMIC_ACQUIRE,
                                         __HIP_MEMORY_SCOPE_AGENT) < t) {}
            }
            __syncthreads();
            __threadfence();             // acquire: invalidate stale caches
            // stage h (2 KB) into LDS: 256 threads x 8 B
            *(uint2*)&hsm[tid * 4] = *(const uint2*)&hin[tid * 4];
            __syncthreads();

            #pragma unroll
            for (int kk = 0; kk < 64; ++kk) {
                half8 hv = *(const half8*)&hsm[kbase + kk * 8];  // wave-uniform: broadcast
                half8 w  = wreg[kk];
                a0 = dot2(__builtin_shufflevector(hv, hv, 0, 1),
                          __builtin_shufflevector(w,  w,  0, 1), a0);
                a1 = dot2(__builtin_shufflevector(hv, hv, 2, 3),
                          __builtin_shufflevector(w,  w,  2, 3), a1);
                a2 = dot2(__builtin_shufflevector(hv, hv, 4, 5),
                          __builtin_shufflevector(w,  w,  4, 5), a2);
                a3 = dot2(__builtin_shufflevector(hv, hv, 6, 7),
                          __builtin_shufflevector(w,  w,  6, 7), a3);
            }
        }

        float acc = (a0 + a1) + (a2 + a3);
        if (kh) red[col] = acc;
        __syncthreads();
        if (!kh) {
            float s = acc + red[col] + pval + bhreg;
            _Float16* Hout = (((t + 1) & 1) ? H1 : H0) + (size_t)b * HID;
            Hout[n0 + col] = (_Float16)tanhf(s);
        }
        __syncthreads();                 // all slice stores issued & drained
        if (tid == 0) {
            __threadfence();             // release: writeback to coherent point
            __hip_atomic_store(&flg[j], t + 1, __ATOMIC_RELEASE,
                               __HIP_MEMORY_SCOPE_AGENT);
        }
    }

    // --- head: WG 0 waits for every chain to finish, then pooled softmax ---
    if (wg == 0) {
        if (tid < NWG) {
            while (__hip_atomic_load(&flags[tid], __ATOMIC_ACQUIRE,
                                     __HIP_MEMORY_SCOPE_AGENT) < T_STEPS) {}
        }
        __syncthreads();
        __threadfence();
        if (tid < 64) {
            const _Float16* R = H0;      // h_256 lands in parity-0 buffer
            float l0 = 0.f, l1 = 0.f;
            for (int c = tid; c < HID; c += 64) {
                float s = 0.f;
                for (int bb = 0; bb < BATCH; ++bb) s += (float)R[(size_t)bb * HID + c];
                float pooled = s * (1.0f / BATCH);
                l0 += pooled * fcw[c * 2 + 0];
                l1 += pooled * fcw[c * 2 + 1];
            }
            #pragma unroll
            for (int off = 32; off > 0; off >>= 1) {
                l0 += __shfl_down(l0, off);
                l1 += __shfl_down(l1, off);
            }
            if (tid == 0) {
                l0 += fcb[0]; l1 += fcb[1];
                float mx = fmaxf(l0, l1);
                float e0 = __expf(l0 - mx), e1 = __expf(l1 - mx);
                float inv = 1.0f / (e0 + e1);
                out[0] = e0 * inv;
                out[1] = e1 * inv;
            }
        }
    }
}

// ===========================================================================
extern "C" void kernel_launch(void* const* d_in, const int* in_sizes, int n_in,
                              void* d_out, int out_size, void* d_ws, size_t ws_size,
                              hipStream_t stream) {
    const float* X   = (const float*)d_in[0];
    const float* Wxh = (const float*)d_in[1];
    const float* Whh = (const float*)d_in[2];
    const float* bh  = (const float*)d_in[3];
    const float* fcw = (const float*)d_in[4];
    const float* fcb = (const float*)d_in[5];

    char* ws = (char*)d_ws;
    float*    P   = (float*)ws;
    _Float16* Bt  = (_Float16*)(ws + OFF_BT);
    _Float16* H0  = (_Float16*)(ws + OFF_H0);
    _Float16* H1  = (_Float16*)(ws + OFF_H1);
    int*      flg = (int*)(ws + OFF_FLG);

    hipLaunchKernelGGL(k_transpose, dim3(500, 16), dim3(256), 0, stream, Wxh, Bt, flg);
    hipLaunchKernelGGL(k_gemm, dim3(448), dim3(256), 0, stream, X, Bt, P);
    hipLaunchKernelGGL(k_rec, dim3(NWG), dim3(256), 0, stream,
                       P, Whh, bh, fcw, fcb, H0, H1, (float*)d_out, flg);
}